// Round 17
// baseline (319.640 us; speedup 1.0000x reference)
//
#include <hip/hip_runtime.h>
#include <math.h>

#define B_   32
#define NCq  62
#define F_   256
#define NE   512
#define M_   (B_*NCq)      // 1984
#define NCOL (NCq*F_)      // 15872
#define NZ   (M_*NCq)      // 123008
#define EPSF 1e-6f

typedef _Float16 h8_t __attribute__((ext_vector_type(8)));
typedef _Float16 h4_t __attribute__((ext_vector_type(4)));
typedef float f4_t __attribute__((ext_vector_type(4)));

__device__ __forceinline__ float eluf(float x){ return x > 0.0f ? x : expm1f(x); }

// XOR-swizzled LDS offset for BK=64: row stride 64 f16 (128B), 8 pieces of 8 f16 (16B)
__device__ __forceinline__ int sw64(int row, int piece){
    return row*64 + ((piece ^ (row&7))*8);
}
// async global->LDS, 16B per lane; lds base wave-uniform, lane i lands at base+i*16
__device__ __forceinline__ void gl_lds(const _Float16* g, _Float16* l){
    __builtin_amdgcn_global_load_lds((const __attribute__((address_space(1))) void*)g,
                                     (__attribute__((address_space(3))) void*)l, 16, 0, 0);
}

// ---------------- fused prep: theta transpose+f16 | codebook prep | o,t ----------------
#define NB_SPLIT (496*8)
#define NB_PREP  NE
#define NB_OT    M_
__global__ __launch_bounds__(256) void k_pre(const float* __restrict__ TH, _Float16* __restrict__ THf,
                                             const float* __restrict__ cb, _Float16* __restrict__ CBf,
                                             float* __restrict__ cnorm, float* __restrict__ out_cb,
                                             const float* __restrict__ x, const float* __restrict__ p,
                                             const float* __restrict__ bias, const float* __restrict__ q,
                                             _Float16* __restrict__ Tf){
    int bid = blockIdx.x;
    int tid = threadIdx.x;
    if(bid < NB_SPLIT){
        __shared__ float tile[32][33];
        int n0 = (bid % 496) * 32, k0 = (bid / 496) * 32;
        int cc = tid & 31, rr = tid >> 5;
        #pragma unroll
        for(int pp=0;pp<4;pp++){
            int kk = rr + pp*8;
            tile[kk][cc] = TH[(size_t)(k0+kk)*NCOL + n0 + cc];
        }
        __syncthreads();
        {
            int nn = tid & 31, kg = tid >> 5;
            h4_t v;
            #pragma unroll
            for(int i=0;i<4;i++) v[i] = (_Float16)tile[kg*4 + i][nn];
            *(h4_t*)&THf[(size_t)(n0+nn)*F_ + k0 + kg*4] = v;
        }
    } else if(bid < NB_SPLIT + NB_PREP){
        int e = bid - NB_SPLIT; int d = tid;
        float v = cb[e*F_ + d];
        out_cb[e*F_ + d] = v;
        CBf[e*F_ + d] = (_Float16)v;
        float s = v*v;
        #pragma unroll
        for(int m=32;m;m>>=1) s += __shfl_xor(s, m, 64);
        __shared__ float red[4];
        if((tid & 63)==0) red[tid>>6] = s;
        __syncthreads();
        if(tid==0) cnorm[e] = red[0]+red[1]+red[2]+red[3];
    } else {
        int bi = bid - NB_SPLIT - NB_PREP; int d = tid;
        int b = bi / NCq, i = bi % NCq;
        __shared__ float pr[NCq];
        __shared__ float orow[F_];
        if(d < NCq) pr[d] = p[i*NCq + d];
        __syncthreads();
        float acc = bias[i*F_ + d];
        const float* xb = x + (size_t)b*NCq*F_ + d;
        #pragma unroll 2
        for(int j=0;j<NCq;j++) acc = fmaf(pr[j], xb[j*F_], acc);
        orow[d] = acc;
        __syncthreads();
        float t = 0.f;
        #pragma unroll 4
        for(int k=0;k<F_;k++) t = fmaf(orow[k], q[k*F_ + d], t);
        Tf[bi*F_ + d] = (_Float16)t;
    }
}

// ---------------- G = ELU(T @ theta), f16 in/out, BK=64, 16x16x32 MFMA (R15 config) ----------------
__global__ __launch_bounds__(256,2) void k_gemm_g(const _Float16* __restrict__ Tf,
                                                  const _Float16* __restrict__ THf,
                                                  _Float16* __restrict__ Gf){
    __shared__ _Float16 As[128*64], Bs[256*64];  // 48 KB
    int tid = threadIdx.x;
    int l = tid & 63, w = tid >> 6;
    int wr = w >> 1, wc = w & 1;
    int m = l & 15, quad = l >> 4;
    int row0 = blockIdx.x * 128, col0 = blockIdx.y * 256;
    int wbase = tid & 192;
    f4_t acc[4][8] = {};
    for(int kc=0; kc<F_; kc+=64){
        #pragma unroll
        for(int p2=0;p2<4;p2++){
            int idx = p2*256 + tid;
            int row = idx >> 3, psw = idx & 7;
            int porig = psw ^ (row&7);
            int rclamp = row0 + row; if(rclamp >= M_) rclamp = M_-1;
            gl_lds(&Tf[(size_t)rclamp*F_ + kc + porig*8], &As[(p2*256 + wbase)*8]);
        }
        #pragma unroll
        for(int p2=0;p2<8;p2++){
            int idx = p2*256 + tid;
            int row = idx >> 3, psw = idx & 7;
            int porig = psw ^ (row&7);
            gl_lds(&THf[(size_t)(col0 + row)*F_ + kc + porig*8], &Bs[(p2*256 + wbase)*8]);
        }
        __syncthreads();
        #pragma unroll
        for(int ks=0;ks<2;ks++){
            h8_t a[4];
            #pragma unroll
            for(int mt=0;mt<4;mt++){
                int row = wr*64 + mt*16 + m;
                a[mt] = *(const h8_t*)&As[sw64(row, ks*4 + quad)];
            }
            #pragma unroll
            for(int nt=0;nt<8;nt++){
                int col = wc*128 + nt*16 + m;
                h8_t b = *(const h8_t*)&Bs[sw64(col, ks*4 + quad)];
                #pragma unroll
                for(int mt=0;mt<4;mt++)
                    acc[mt][nt] = __builtin_amdgcn_mfma_f32_16x16x32_f16(a[mt], b, acc[mt][nt], 0,0,0);
            }
        }
        __syncthreads();
    }
    #pragma unroll
    for(int mt=0;mt<4;mt++){
        #pragma unroll
        for(int nt=0;nt<8;nt++){
            int rowb = row0 + wr*64 + mt*16 + quad*4;
            int colb = col0 + wc*128 + nt*16 + m;
            #pragma unroll
            for(int r=0;r<4;r++){
                int row = rowb + r;
                if(row < M_) Gf[(size_t)row*NCOL + colb] = (_Float16)eluf(acc[mt][nt][r]);
            }
        }
    }
}

// ---------------- den + loss partial; renormalize Gf IN PLACE to f16 z ----------------
__global__ __launch_bounds__(256) void k_den(_Float16* __restrict__ Gf, float* __restrict__ lp){
    int bi = blockIdx.x;
    int tid = threadIdx.x;
    int dg = tid & 31, jg = tid >> 5;
    __shared__ float l1[8][32][8];
    __shared__ float l2[8][32][8];
    __shared__ float invsh[32][8];
    float v[8][8];
    float a1[8] = {}, a2[8] = {};
    size_t base = (size_t)bi*NCOL + dg*8;
    #pragma unroll
    for(int p=0;p<8;p++){
        int j = jg + p*8;
        if(j < NCq){
            h8_t g = *(const h8_t*)&Gf[base + (size_t)j*F_];
            #pragma unroll
            for(int i=0;i<8;i++){
                float t = (float)g[i];
                v[p][i] = t;
                a1[i] += fabsf(t);
                a2[i] = fmaf(t, t, a2[i]);
            }
        }
    }
    #pragma unroll
    for(int i=0;i<8;i++){ l1[jg][dg][i] = a1[i]; l2[jg][dg][i] = a2[i]; }
    __syncthreads();
    if(jg == 0){
        float part = 0.f;
        #pragma unroll
        for(int i=0;i<8;i++){
            float s1 = 0.f, s2 = 0.f;
            #pragma unroll
            for(int q2=0;q2<8;q2++){ s1 += l1[q2][dg][i]; s2 += l2[q2][dg][i]; }
            float inv = 1.0f/(s1 + EPSF);
            invsh[dg][i] = inv;
            part += s2*inv*inv;
        }
        #pragma unroll
        for(int mk=16;mk;mk>>=1) part += __shfl_xor(part, mk, 32);
        if(tid == 0) lp[bi] = part;
    }
    __syncthreads();
    float inv[8];
    #pragma unroll
    for(int i=0;i<8;i++) inv[i] = invsh[dg][i];
    #pragma unroll
    for(int p=0;p<8;p++){
        int j = jg + p*8;
        if(j < NCq){
            h8_t z;
            #pragma unroll
            for(int i=0;i<8;i++) z[i] = (_Float16)(v[p][i]*inv[i]);
            *(h8_t*)&Gf[base + (size_t)j*F_] = z;
        }
    }
}

// ---------------- VQ: dist GEMM (f16 16x16x32 MFMA, BK=64) + argmin ----------------
// block 128 rows x 128 codes; acc[4][4]=64 AGPR; (256,3) -> 12 waves/CU, ~170 reg budget
__global__ __launch_bounds__(256,3) void k_vq(const _Float16* __restrict__ Zf,
                                              const _Float16* __restrict__ CBf,
                                              const float* __restrict__ cnorm,
                                              float* __restrict__ pmin, int* __restrict__ pidx){
    __shared__ _Float16 As[128*64], Bs[128*64];   // 32 KB
    int tid = threadIdx.x;
    int l = tid & 63, w = tid >> 6;
    int wr = w >> 1, wc = w & 1;
    int m = l & 15, quad = l >> 4;
    int n_base = blockIdx.x * 128;
    int e0 = blockIdx.y * 128;
    int wbase = tid & 192;
    f4_t acc[4][4] = {};
    for(int kc=0; kc<F_; kc+=64){
        #pragma unroll
        for(int p2=0;p2<4;p2++){
            int idx = p2*256 + tid;
            int row = idx >> 3, psw = idx & 7;
            int porig = psw ^ (row&7);
            gl_lds(&Zf[(size_t)(n_base + row)*F_ + kc + porig*8], &As[(p2*256 + wbase)*8]);
        }
        #pragma unroll
        for(int p2=0;p2<4;p2++){
            int idx = p2*256 + tid;
            int row = idx >> 3, psw = idx & 7;
            int porig = psw ^ (row&7);
            gl_lds(&CBf[(size_t)(e0 + row)*F_ + kc + porig*8], &Bs[(p2*256 + wbase)*8]);
        }
        __syncthreads();
        #pragma unroll
        for(int ks=0;ks<2;ks++){
            h8_t a[4];
            #pragma unroll
            for(int mt=0;mt<4;mt++){
                int row = wr*64 + mt*16 + m;
                a[mt] = *(const h8_t*)&As[sw64(row, ks*4 + quad)];
            }
            #pragma unroll
            for(int nt=0;nt<4;nt++){
                int col = wc*64 + nt*16 + m;
                h8_t b = *(const h8_t*)&Bs[sw64(col, ks*4 + quad)];
                #pragma unroll
                for(int mt=0;mt<4;mt++)
                    acc[mt][nt] = __builtin_amdgcn_mfma_f32_16x16x32_f16(a[mt], b, acc[mt][nt], 0,0,0);
            }
        }
        __syncthreads();
    }
    // epilogue: score = cnorm - 2*dot; argmin over this wave's 64 codes
    #pragma unroll
    for(int mt=0;mt<4;mt++){
        float bv[4]; int bix[4];
        #pragma unroll
        for(int r=0;r<4;r++){ bv[r] = 3.4e38f; bix[r] = 0; }
        #pragma unroll
        for(int nt=0;nt<4;nt++){
            int e = e0 + wc*64 + nt*16 + m;
            float cn = cnorm[e];
            #pragma unroll
            for(int r=0;r<4;r++){
                float vv = cn - 2.0f*acc[mt][nt][r];
                if(vv < bv[r]){ bv[r] = vv; bix[r] = e; }
            }
        }
        #pragma unroll
        for(int r=0;r<4;r++){
            float vv = bv[r]; int ix = bix[r];
            #pragma unroll
            for(int mk=8;mk;mk>>=1){
                float ov = __shfl_xor(vv, mk, 64);
                int   oi = __shfl_xor(ix, mk, 64);
                if(ov < vv || (ov == vv && oi < ix)){ vv = ov; ix = oi; }
            }
            if(m == 0){
                int n = n_base + wr*64 + mt*16 + quad*4 + r;
                int slot = blockIdx.y*2 + wc;   // 8 ascending code ranges
                pmin[(size_t)n*8 + slot] = vv;
                pidx[(size_t)n*8 + slot] = ix;
            }
        }
    }
}

// ---------------- fused post: argmin finalize + hist + SE + wtab + output ----------------
__global__ __launch_bounds__(1024) void k_post(const float* __restrict__ pmin, const int* __restrict__ pidx,
                                               int* __restrict__ idx, int* __restrict__ countb,
                                               float* __restrict__ lossb,
                                               const float* __restrict__ cb,
                                               const float* __restrict__ w1, const float* __restrict__ b1,
                                               const float* __restrict__ w2, const float* __restrict__ b2,
                                               float* __restrict__ out){
    int b = blockIdx.x;
    int t = threadIdx.x;
    __shared__ int hist[NE];
    __shared__ float red[16];
    __shared__ float sp[4][F_];
    __shared__ float s_sh[F_];
    __shared__ float h_sh[16];
    __shared__ float s2p1[F_];
    __shared__ float wt[NE];
    for(int e=t; e<NE; e+=1024) hist[e] = 0;
    __syncthreads();
    float msum = 0.f;
    int n0 = b * (NCq*NCq);
    for(int i=t; i<NCq*NCq; i+=1024){
        int n = n0 + i;
        float bv = 3.4e38f; int bix = 0;
        #pragma unroll
        for(int c=0;c<2;c++){
            float4 pv = *(const float4*)&pmin[(size_t)n*8 + c*4];
            int4   pi = *(const int4*)&pidx[(size_t)n*8 + c*4];
            if(pv.x < bv || (pv.x==bv && pi.x<bix)){ bv=pv.x; bix=pi.x; }
            if(pv.y < bv || (pv.y==bv && pi.y<bix)){ bv=pv.y; bix=pi.y; }
            if(pv.z < bv || (pv.z==bv && pi.z<bix)){ bv=pv.z; bix=pi.z; }
            if(pv.w < bv || (pv.w==bv && pi.w<bix)){ bv=pv.w; bix=pi.w; }
        }
        idx[n] = bix;
        atomicAdd(&hist[bix], 1);
        msum += bv;
    }
    #pragma unroll
    for(int m=32;m;m>>=1) msum += __shfl_xor(msum, m, 64);
    if((t&63)==0) red[t>>6] = msum;
    __syncthreads();
    if(t==0){
        float s = 0.f;
        #pragma unroll
        for(int i2=0;i2<16;i2++) s += red[i2];
        lossb[b] = s;
    }
    for(int e=t; e<NE; e+=1024) countb[b*NE + e] = hist[e];
    {
        int d = t & 255, qq = t >> 8;
        float s = 0.f;
        for(int e=qq*128; e<(qq+1)*128; e++) s = fmaf((float)hist[e], cb[e*F_ + d], s);
        sp[qq][d] = s;
    }
    __syncthreads();
    if(t < F_) s_sh[t] = (sp[0][t]+sp[1][t]+sp[2][t]+sp[3][t]) * (1.0f/(float)(NCq*NCq));
    __syncthreads();
    if(t < 16){
        float h = b1[t];
        for(int k=0;k<F_;k++) h = fmaf(s_sh[k], w1[k*16 + t], h);
        h_sh[t] = fmaxf(h, 0.f);
    }
    __syncthreads();
    if(t < F_){
        float v = b2[t];
        #pragma unroll
        for(int r=0;r<16;r++) v = fmaf(h_sh[r], w2[r*F_ + t], v);
        s2p1[t] = 1.0f + 1.0f/(1.0f + expf(-v));
    }
    __syncthreads();
    {
        int wv = t >> 6, lane = t & 63;
        for(int e = wv; e < NE; e += 16){
            float4 c4 = *(const float4*)&cb[e*F_ + lane*4];
            float s = eluf(c4.x*s2p1[lane*4]) + eluf(c4.y*s2p1[lane*4+1])
                    + eluf(c4.z*s2p1[lane*4+2]) + eluf(c4.w*s2p1[lane*4+3]);
            #pragma unroll
            for(int m2=32;m2;m2>>=1) s += __shfl_xor(s, m2, 64);
            if(lane==0) wt[e] = s;
        }
    }
    __syncthreads();
    {
        int wv = t >> 6, lane = t & 63;
        for(int i = wv; i < NCq; i += 16){
            int bi = b*NCq + i;
            float v = 0.f;
            if(lane < NCq) v = eluf(wt[idx[bi*NCq + lane]]);
            float a = fabsf(v);
            #pragma unroll
            for(int m2=32;m2;m2>>=1) a += __shfl_xor(a, m2, 64);
            if(lane < NCq) out[1 + bi*NCq + lane] = v / (a + EPSF);
        }
    }
}

// ---------------- scalars: vq_loss and usage (from partials) ----------------
__global__ __launch_bounds__(256) void k_scal(const int* __restrict__ countb,
                                              const float* __restrict__ lp, const float* __restrict__ lossb,
                                              float* __restrict__ out){
    int t = threadIdx.x;
    float ent = 0.f;
    for(int e=t; e<NE; e+=256){
        int c = 0;
        #pragma unroll 4
        for(int b=0;b<B_;b++) c += countb[b*NE + e];
        float pr = (float)c / (float)NZ;
        ent += pr * logf(pr + 1e-10f);
    }
    float ls = 0.f;
    for(int i=t; i<M_; i+=256) ls += lp[i];
    if(t < B_) ls += lossb[t];
    #pragma unroll
    for(int m=32;m;m>>=1){ ent += __shfl_xor(ent,m,64); ls += __shfl_xor(ls,m,64); }
    __shared__ float red[4], red2[4];
    if((t&63)==0){ red[t>>6]=ent; red2[t>>6]=ls; }
    __syncthreads();
    if(t==0){
        float e2 = red[0]+red[1]+red[2]+red[3];
        float l2 = red2[0]+red2[1]+red2[2]+red2[3];
        out[1+NZ] = expf(-e2);
        out[0] = (float)(1.25 * (double)l2 / ((double)NZ * (double)F_));
    }
}

extern "C" void kernel_launch(void* const* d_in, const int* in_sizes, int n_in,
                              void* d_out, int out_size, void* d_ws, size_t ws_size,
                              hipStream_t stream){
    (void)in_sizes; (void)n_in; (void)out_size; (void)ws_size;
    const float* x    = (const float*)d_in[0];
    const float* p    = (const float*)d_in[1];
    const float* bias = (const float*)d_in[2];
    const float* q    = (const float*)d_in[3];
    const float* th   = (const float*)d_in[4];
    const float* cb   = (const float*)d_in[5];
    const float* w1   = (const float*)d_in[6];
    const float* b1   = (const float*)d_in[7];
    const float* w2   = (const float*)d_in[8];
    const float* b2   = (const float*)d_in[9];
    float* out = (float*)d_out;
    char* ws = (char*)d_ws;
    size_t off = 0;
    auto alloc = [&](size_t bytes){ void* ptr = ws + off; off = (off + bytes + 255) & ~255ull; return ptr; };
    _Float16* Gf   = (_Float16*)alloc((size_t)NZ*F_*sizeof(_Float16));      // 60 MiB (doubles as Zf)
    _Float16* THf  = (_Float16*)alloc((size_t)F_*NCOL*sizeof(_Float16));    // 7.75 MiB ([n][k])
    _Float16* Tf   = (_Float16*)alloc((size_t)M_*F_*sizeof(_Float16));
    _Float16* CBf  = (_Float16*)alloc((size_t)NE*F_*sizeof(_Float16));
    float*    CN   = (float*)   alloc((size_t)NE*sizeof(float));
    float*    PMIN = (float*)   alloc((size_t)NZ*8*sizeof(float));
    int*      PIDX = (int*)     alloc((size_t)NZ*8*sizeof(int));
    int*      IDX  = (int*)     alloc((size_t)NZ*sizeof(int));
    float*    LP    = (float*)  alloc((size_t)M_*sizeof(float));
    float*    LOSSB = (float*)  alloc((size_t)B_*sizeof(float));
    int*      COUNTB= (int*)    alloc((size_t)B_*NE*sizeof(int));

    k_pre<<<NB_SPLIT + NB_PREP + NB_OT, 256, 0, stream>>>(th, THf, cb, CBf, CN, out + 1 + NZ + 1,
                                                          x, p, bias, q, Tf);
    dim3 g3((M_ + 127)/128, NCOL/256);   // 16 x 62
    k_gemm_g<<<g3, 256, 0, stream>>>(Tf, THf, Gf);
    k_den<<<M_, 256, 0, stream>>>(Gf, LP);
    dim3 g5(NZ/128, 4);                  // 961 x 4
    k_vq<<<g5, 256, 0, stream>>>(Gf, CBf, CN, PMIN, PIDX);
    k_post<<<B_, 1024, 0, stream>>>(PMIN, PIDX, IDX, COUNTB, LOSSB, cb, w1, b1, w2, b2, out);
    k_scal<<<1, 256, 0, stream>>>(COUNTB, LP, LOSSB, out);
}

// Round 18
// 285.645 us; speedup vs baseline: 1.1190x; 1.1190x over previous
//
#include <hip/hip_runtime.h>
#include <math.h>

#define B_   32
#define NCq  62
#define F_   256
#define NE   512
#define M_   (B_*NCq)      // 1984
#define NCOL (NCq*F_)      // 15872
#define NZ   (M_*NCq)      // 123008
#define EPSF 1e-6f

typedef _Float16 h8_t __attribute__((ext_vector_type(8)));
typedef _Float16 h4_t __attribute__((ext_vector_type(4)));
typedef float f4_t __attribute__((ext_vector_type(4)));

__device__ __forceinline__ float eluf(float x){ return x > 0.0f ? x : expm1f(x); }

// XOR-swizzled LDS offset for BK=64: row stride 64 f16 (128B), 8 pieces of 8 f16 (16B)
__device__ __forceinline__ int sw64(int row, int piece){
    return row*64 + ((piece ^ (row&7))*8);
}
// async global->LDS, 16B per lane; lds base wave-uniform, lane i lands at base+i*16
__device__ __forceinline__ void gl_lds(const _Float16* g, _Float16* l){
    __builtin_amdgcn_global_load_lds((const __attribute__((address_space(1))) void*)g,
                                     (__attribute__((address_space(3))) void*)l, 16, 0, 0);
}

// ---------------- fused prep: theta transpose+f16 | codebook prep | o,t ----------------
#define NB_SPLIT (496*8)
#define NB_PREP  NE
#define NB_OT    M_
__global__ __launch_bounds__(256) void k_pre(const float* __restrict__ TH, _Float16* __restrict__ THf,
                                             const float* __restrict__ cb, _Float16* __restrict__ CBf,
                                             float* __restrict__ cnorm, float* __restrict__ out_cb,
                                             const float* __restrict__ x, const float* __restrict__ p,
                                             const float* __restrict__ bias, const float* __restrict__ q,
                                             _Float16* __restrict__ Tf){
    int bid = blockIdx.x;
    int tid = threadIdx.x;
    if(bid < NB_SPLIT){
        __shared__ float tile[32][33];
        int n0 = (bid % 496) * 32, k0 = (bid / 496) * 32;
        int cc = tid & 31, rr = tid >> 5;
        #pragma unroll
        for(int pp=0;pp<4;pp++){
            int kk = rr + pp*8;
            tile[kk][cc] = TH[(size_t)(k0+kk)*NCOL + n0 + cc];
        }
        __syncthreads();
        // vectorized transposed store: thread owns (nn = tid&31, kg = tid>>5 in 0..7),
        // 4 k-values each: 256 threads x 4 = 1024 = full 32x32 tile (coverage verified)
        {
            int nn = tid & 31, kg = tid >> 5;
            h4_t v;
            #pragma unroll
            for(int i=0;i<4;i++) v[i] = (_Float16)tile[kg*4 + i][nn];
            *(h4_t*)&THf[(size_t)(n0+nn)*F_ + k0 + kg*4] = v;
        }
    } else if(bid < NB_SPLIT + NB_PREP){
        int e = bid - NB_SPLIT; int d = tid;
        float v = cb[e*F_ + d];
        out_cb[e*F_ + d] = v;
        CBf[e*F_ + d] = (_Float16)v;
        float s = v*v;
        #pragma unroll
        for(int m=32;m;m>>=1) s += __shfl_xor(s, m, 64);
        __shared__ float red[4];
        if((tid & 63)==0) red[tid>>6] = s;
        __syncthreads();
        if(tid==0) cnorm[e] = red[0]+red[1]+red[2]+red[3];
    } else {
        int bi = bid - NB_SPLIT - NB_PREP; int d = tid;
        int b = bi / NCq, i = bi % NCq;
        __shared__ float pr[NCq];
        __shared__ float orow[F_];
        if(d < NCq) pr[d] = p[i*NCq + d];
        __syncthreads();
        float acc = bias[i*F_ + d];
        const float* xb = x + (size_t)b*NCq*F_ + d;
        #pragma unroll 2
        for(int j=0;j<NCq;j++) acc = fmaf(pr[j], xb[j*F_], acc);
        orow[d] = acc;
        __syncthreads();
        float t = 0.f;
        #pragma unroll 4
        for(int k=0;k<F_;k++) t = fmaf(orow[k], q[k*F_ + d], t);
        Tf[bi*F_ + d] = (_Float16)t;
    }
}

// ---------------- G = ELU(T @ theta), f16 in/out, BK=64, 16x16x32 MFMA ----------------
__global__ __launch_bounds__(256,2) void k_gemm_g(const _Float16* __restrict__ Tf,
                                                  const _Float16* __restrict__ THf,
                                                  _Float16* __restrict__ Gf){
    __shared__ _Float16 As[128*64], Bs[256*64];  // 48 KB
    int tid = threadIdx.x;
    int l = tid & 63, w = tid >> 6;
    int wr = w >> 1, wc = w & 1;
    int m = l & 15, quad = l >> 4;
    int row0 = blockIdx.x * 128, col0 = blockIdx.y * 256;
    int wbase = tid & 192;
    f4_t acc[4][8] = {};
    for(int kc=0; kc<F_; kc+=64){
        #pragma unroll
        for(int p2=0;p2<4;p2++){
            int idx = p2*256 + tid;
            int row = idx >> 3, psw = idx & 7;
            int porig = psw ^ (row&7);
            int rclamp = row0 + row; if(rclamp >= M_) rclamp = M_-1;
            gl_lds(&Tf[(size_t)rclamp*F_ + kc + porig*8], &As[(p2*256 + wbase)*8]);
        }
        #pragma unroll
        for(int p2=0;p2<8;p2++){
            int idx = p2*256 + tid;
            int row = idx >> 3, psw = idx & 7;
            int porig = psw ^ (row&7);
            gl_lds(&THf[(size_t)(col0 + row)*F_ + kc + porig*8], &Bs[(p2*256 + wbase)*8]);
        }
        __syncthreads();
        #pragma unroll
        for(int ks=0;ks<2;ks++){
            h8_t a[4];
            #pragma unroll
            for(int mt=0;mt<4;mt++){
                int row = wr*64 + mt*16 + m;
                a[mt] = *(const h8_t*)&As[sw64(row, ks*4 + quad)];
            }
            #pragma unroll
            for(int nt=0;nt<8;nt++){
                int col = wc*128 + nt*16 + m;
                h8_t b = *(const h8_t*)&Bs[sw64(col, ks*4 + quad)];
                #pragma unroll
                for(int mt=0;mt<4;mt++)
                    acc[mt][nt] = __builtin_amdgcn_mfma_f32_16x16x32_f16(a[mt], b, acc[mt][nt], 0,0,0);
            }
        }
        __syncthreads();
    }
    #pragma unroll
    for(int mt=0;mt<4;mt++){
        #pragma unroll
        for(int nt=0;nt<8;nt++){
            int rowb = row0 + wr*64 + mt*16 + quad*4;
            int colb = col0 + wc*128 + nt*16 + m;
            #pragma unroll
            for(int r=0;r<4;r++){
                int row = rowb + r;
                if(row < M_) Gf[(size_t)row*NCOL + colb] = (_Float16)eluf(acc[mt][nt][r]);
            }
        }
    }
}

// ---------------- den + loss partial; renormalize Gf IN PLACE to f16 z ----------------
__global__ __launch_bounds__(256) void k_den(_Float16* __restrict__ Gf, float* __restrict__ lp){
    int bi = blockIdx.x;
    int tid = threadIdx.x;
    int dg = tid & 31, jg = tid >> 5;
    __shared__ float l1[8][32][8];
    __shared__ float l2[8][32][8];
    __shared__ float invsh[32][8];
    float v[8][8];
    float a1[8] = {}, a2[8] = {};
    size_t base = (size_t)bi*NCOL + dg*8;
    #pragma unroll
    for(int p=0;p<8;p++){
        int j = jg + p*8;
        if(j < NCq){
            h8_t g = *(const h8_t*)&Gf[base + (size_t)j*F_];
            #pragma unroll
            for(int i=0;i<8;i++){
                float t = (float)g[i];
                v[p][i] = t;
                a1[i] += fabsf(t);
                a2[i] = fmaf(t, t, a2[i]);
            }
        }
    }
    #pragma unroll
    for(int i=0;i<8;i++){ l1[jg][dg][i] = a1[i]; l2[jg][dg][i] = a2[i]; }
    __syncthreads();
    if(jg == 0){
        float part = 0.f;
        #pragma unroll
        for(int i=0;i<8;i++){
            float s1 = 0.f, s2 = 0.f;
            #pragma unroll
            for(int q2=0;q2<8;q2++){ s1 += l1[q2][dg][i]; s2 += l2[q2][dg][i]; }
            float inv = 1.0f/(s1 + EPSF);
            invsh[dg][i] = inv;
            part += s2*inv*inv;
        }
        #pragma unroll
        for(int mk=16;mk;mk>>=1) part += __shfl_xor(part, mk, 32);
        if(tid == 0) lp[bi] = part;
    }
    __syncthreads();
    float inv[8];
    #pragma unroll
    for(int i=0;i<8;i++) inv[i] = invsh[dg][i];
    #pragma unroll
    for(int p=0;p<8;p++){
        int j = jg + p*8;
        if(j < NCq){
            h8_t z;
            #pragma unroll
            for(int i=0;i<8;i++) z[i] = (_Float16)(v[p][i]*inv[i]);
            *(h8_t*)&Gf[base + (size_t)j*F_] = z;
        }
    }
}

// ---------------- VQ: dist GEMM (f16 16x16x32 MFMA, BK=64, single buffer) + argmin ----------------
__global__ __launch_bounds__(256,2) void k_vq(const _Float16* __restrict__ Zf,
                                              const _Float16* __restrict__ CBf,
                                              const float* __restrict__ cnorm,
                                              float* __restrict__ pmin, int* __restrict__ pidx){
    __shared__ _Float16 As[128*64], Bs[256*64];   // 48 KB
    int tid = threadIdx.x;
    int l = tid & 63, w = tid >> 6;
    int wr = w >> 1, wc = w & 1;
    int m = l & 15, quad = l >> 4;
    int n_base = blockIdx.x * 128;
    int e0 = blockIdx.y * 256;
    int wbase = tid & 192;
    f4_t acc[4][8] = {};
    for(int kc=0; kc<F_; kc+=64){
        #pragma unroll
        for(int p2=0;p2<4;p2++){
            int idx = p2*256 + tid;
            int row = idx >> 3, psw = idx & 7;
            int porig = psw ^ (row&7);
            gl_lds(&Zf[(size_t)(n_base + row)*F_ + kc + porig*8], &As[(p2*256 + wbase)*8]);
        }
        #pragma unroll
        for(int p2=0;p2<8;p2++){
            int idx = p2*256 + tid;
            int row = idx >> 3, psw = idx & 7;
            int porig = psw ^ (row&7);
            gl_lds(&CBf[(size_t)(e0 + row)*F_ + kc + porig*8], &Bs[(p2*256 + wbase)*8]);
        }
        __syncthreads();
        #pragma unroll
        for(int ks=0;ks<2;ks++){
            h8_t a[4];
            #pragma unroll
            for(int mt=0;mt<4;mt++){
                int row = wr*64 + mt*16 + m;
                a[mt] = *(const h8_t*)&As[sw64(row, ks*4 + quad)];
            }
            #pragma unroll
            for(int nt=0;nt<8;nt++){
                int col = wc*128 + nt*16 + m;
                h8_t b = *(const h8_t*)&Bs[sw64(col, ks*4 + quad)];
                #pragma unroll
                for(int mt=0;mt<4;mt++)
                    acc[mt][nt] = __builtin_amdgcn_mfma_f32_16x16x32_f16(a[mt], b, acc[mt][nt], 0,0,0);
            }
        }
        __syncthreads();
    }
    #pragma unroll
    for(int mt=0;mt<4;mt++){
        float bv[4]; int bix[4];
        #pragma unroll
        for(int r=0;r<4;r++){ bv[r] = 3.4e38f; bix[r] = 0; }
        #pragma unroll
        for(int nt=0;nt<8;nt++){
            int e = e0 + wc*128 + nt*16 + m;
            float cn = cnorm[e];
            #pragma unroll
            for(int r=0;r<4;r++){
                float vv = cn - 2.0f*acc[mt][nt][r];
                if(vv < bv[r]){ bv[r] = vv; bix[r] = e; }
            }
        }
        #pragma unroll
        for(int r=0;r<4;r++){
            float vv = bv[r]; int ix = bix[r];
            #pragma unroll
            for(int mk=8;mk;mk>>=1){
                float ov = __shfl_xor(vv, mk, 64);
                int   oi = __shfl_xor(ix, mk, 64);
                if(ov < vv || (ov == vv && oi < ix)){ vv = ov; ix = oi; }
            }
            if(m == 0){
                int n = n_base + wr*64 + mt*16 + quad*4 + r;
                int slot = blockIdx.y*2 + wc;
                pmin[n*4 + slot] = vv;
                pidx[n*4 + slot] = ix;
            }
        }
    }
}

// ---------------- fused post: argmin finalize + hist + SE + wtab + output ----------------
__global__ __launch_bounds__(1024) void k_post(const float* __restrict__ pmin, const int* __restrict__ pidx,
                                               int* __restrict__ idx, int* __restrict__ countb,
                                               float* __restrict__ lossb,
                                               const float* __restrict__ cb,
                                               const float* __restrict__ w1, const float* __restrict__ b1,
                                               const float* __restrict__ w2, const float* __restrict__ b2,
                                               float* __restrict__ out){
    int b = blockIdx.x;
    int t = threadIdx.x;
    __shared__ int hist[NE];
    __shared__ float red[16];
    __shared__ float sp[4][F_];
    __shared__ float s_sh[F_];
    __shared__ float h_sh[16];
    __shared__ float s2p1[F_];
    __shared__ float wt[NE];
    for(int e=t; e<NE; e+=1024) hist[e] = 0;
    __syncthreads();
    float msum = 0.f;
    int n0 = b * (NCq*NCq);
    for(int i=t; i<NCq*NCq; i+=1024){
        int n = n0 + i;
        float4 pv = *(const float4*)&pmin[n*4];
        int4   pi = *(const int4*)&pidx[n*4];
        float bv = pv.x; int bix = pi.x;
        if(pv.y < bv || (pv.y==bv && pi.y<bix)){ bv=pv.y; bix=pi.y; }
        if(pv.z < bv || (pv.z==bv && pi.z<bix)){ bv=pv.z; bix=pi.z; }
        if(pv.w < bv || (pv.w==bv && pi.w<bix)){ bv=pv.w; bix=pi.w; }
        idx[n] = bix;
        atomicAdd(&hist[bix], 1);
        msum += bv;
    }
    #pragma unroll
    for(int m=32;m;m>>=1) msum += __shfl_xor(msum, m, 64);
    if((t&63)==0) red[t>>6] = msum;
    __syncthreads();
    if(t==0){
        float s = 0.f;
        #pragma unroll
        for(int i2=0;i2<16;i2++) s += red[i2];
        lossb[b] = s;
    }
    for(int e=t; e<NE; e+=1024) countb[b*NE + e] = hist[e];
    {
        int d = t & 255, qq = t >> 8;
        float s = 0.f;
        for(int e=qq*128; e<(qq+1)*128; e++) s = fmaf((float)hist[e], cb[e*F_ + d], s);
        sp[qq][d] = s;
    }
    __syncthreads();
    if(t < F_) s_sh[t] = (sp[0][t]+sp[1][t]+sp[2][t]+sp[3][t]) * (1.0f/(float)(NCq*NCq));
    __syncthreads();
    if(t < 16){
        float h = b1[t];
        for(int k=0;k<F_;k++) h = fmaf(s_sh[k], w1[k*16 + t], h);
        h_sh[t] = fmaxf(h, 0.f);
    }
    __syncthreads();
    if(t < F_){
        float v = b2[t];
        #pragma unroll
        for(int r=0;r<16;r++) v = fmaf(h_sh[r], w2[r*F_ + t], v);
        s2p1[t] = 1.0f + 1.0f/(1.0f + expf(-v));
    }
    __syncthreads();
    {
        int wv = t >> 6, lane = t & 63;
        for(int e = wv; e < NE; e += 16){
            float4 c4 = *(const float4*)&cb[e*F_ + lane*4];
            float s = eluf(c4.x*s2p1[lane*4]) + eluf(c4.y*s2p1[lane*4+1])
                    + eluf(c4.z*s2p1[lane*4+2]) + eluf(c4.w*s2p1[lane*4+3]);
            #pragma unroll
            for(int m2=32;m2;m2>>=1) s += __shfl_xor(s, m2, 64);
            if(lane==0) wt[e] = s;
        }
    }
    __syncthreads();
    {
        int wv = t >> 6, lane = t & 63;
        for(int i = wv; i < NCq; i += 16){
            int bi = b*NCq + i;
            float v = 0.f;
            if(lane < NCq) v = eluf(wt[idx[bi*NCq + lane]]);
            float a = fabsf(v);
            #pragma unroll
            for(int m2=32;m2;m2>>=1) a += __shfl_xor(a, m2, 64);
            if(lane < NCq) out[1 + bi*NCq + lane] = v / (a + EPSF);
        }
    }
}

// ---------------- scalars: vq_loss and usage (from partials) ----------------
__global__ __launch_bounds__(256) void k_scal(const int* __restrict__ countb,
                                              const float* __restrict__ lp, const float* __restrict__ lossb,
                                              float* __restrict__ out){
    int t = threadIdx.x;
    float ent = 0.f;
    for(int e=t; e<NE; e+=256){
        int c = 0;
        #pragma unroll 4
        for(int b=0;b<B_;b++) c += countb[b*NE + e];
        float pr = (float)c / (float)NZ;
        ent += pr * logf(pr + 1e-10f);
    }
    float ls = 0.f;
    for(int i=t; i<M_; i+=256) ls += lp[i];
    if(t < B_) ls += lossb[t];
    #pragma unroll
    for(int m=32;m;m>>=1){ ent += __shfl_xor(ent,m,64); ls += __shfl_xor(ls,m,64); }
    __shared__ float red[4], red2[4];
    if((t&63)==0){ red[t>>6]=ent; red2[t>>6]=ls; }
    __syncthreads();
    if(t==0){
        float e2 = red[0]+red[1]+red[2]+red[3];
        float l2 = red2[0]+red2[1]+red2[2]+red2[3];
        out[1+NZ] = expf(-e2);
        out[0] = (float)(1.25 * (double)l2 / ((double)NZ * (double)F_));
    }
}

extern "C" void kernel_launch(void* const* d_in, const int* in_sizes, int n_in,
                              void* d_out, int out_size, void* d_ws, size_t ws_size,
                              hipStream_t stream){
    (void)in_sizes; (void)n_in; (void)out_size; (void)ws_size;
    const float* x    = (const float*)d_in[0];
    const float* p    = (const float*)d_in[1];
    const float* bias = (const float*)d_in[2];
    const float* q    = (const float*)d_in[3];
    const float* th   = (const float*)d_in[4];
    const float* cb   = (const float*)d_in[5];
    const float* w1   = (const float*)d_in[6];
    const float* b1   = (const float*)d_in[7];
    const float* w2   = (const float*)d_in[8];
    const float* b2   = (const float*)d_in[9];
    float* out = (float*)d_out;
    char* ws = (char*)d_ws;
    size_t off = 0;
    auto alloc = [&](size_t bytes){ void* ptr = ws + off; off = (off + bytes + 255) & ~255ull; return ptr; };
    _Float16* Gf   = (_Float16*)alloc((size_t)NZ*F_*sizeof(_Float16));      // 60 MiB (doubles as Zf)
    _Float16* THf  = (_Float16*)alloc((size_t)F_*NCOL*sizeof(_Float16));    // 7.75 MiB ([n][k])
    _Float16* Tf   = (_Float16*)alloc((size_t)M_*F_*sizeof(_Float16));
    _Float16* CBf  = (_Float16*)alloc((size_t)NE*F_*sizeof(_Float16));
    float*    CN   = (float*)   alloc((size_t)NE*sizeof(float));
    float*    PMIN = (float*)   alloc((size_t)NZ*4*sizeof(float));
    int*      PIDX = (int*)     alloc((size_t)NZ*4*sizeof(int));
    int*      IDX  = (int*)     alloc((size_t)NZ*sizeof(int));
    float*    LP    = (float*)  alloc((size_t)M_*sizeof(float));
    float*    LOSSB = (float*)  alloc((size_t)B_*sizeof(float));
    int*      COUNTB= (int*)    alloc((size_t)B_*NE*sizeof(int));

    k_pre<<<NB_SPLIT + NB_PREP + NB_OT, 256, 0, stream>>>(th, THf, cb, CBf, CN, out + 1 + NZ + 1,
                                                          x, p, bias, q, Tf);
    dim3 g3((M_ + 127)/128, NCOL/256);
    k_gemm_g<<<g3, 256, 0, stream>>>(Tf, THf, Gf);
    k_den<<<M_, 256, 0, stream>>>(Gf, LP);
    dim3 g5(NZ/128, 2);
    k_vq<<<g5, 256, 0, stream>>>(Gf, CBf, CN, PMIN, PIDX);
    k_post<<<B_, 1024, 0, stream>>>(PMIN, PIDX, IDX, COUNTB, LOSSB, cb, w1, b1, w2, b2, out);
    k_scal<<<1, 256, 0, stream>>>(COUNTB, LP, LOSSB, out);
}